// Round 1
// baseline (154.297 us; speedup 1.0000x reference)
//
#include <hip/hip_runtime.h>
#include <hip/hip_bf16.h>
#include <stdint.h>

// ---------- types / helpers ----------
typedef __attribute__((ext_vector_type(8))) short s8v;      // 8 x bf16 (4 VGPR)
typedef __attribute__((ext_vector_type(4))) float f32x4;
typedef __attribute__((ext_vector_type(16))) float f32x16;

union V16 { uint4 u4; unsigned int u[4]; s8v s; };

__device__ inline s8v u4_to_s8(uint4 v) { V16 c; c.u4 = v; return c.s; }
__device__ inline s8v words_to_s8(unsigned int a, unsigned int b, unsigned int c, unsigned int d) {
  V16 t; t.u[0] = a; t.u[1] = b; t.u[2] = c; t.u[3] = d; return t.s;
}
__device__ inline unsigned short f2b(float f) {
  __hip_bfloat16 h = __float2bfloat16(f);
  unsigned short u; __builtin_memcpy(&u, &h, 2); return u;
}
__device__ inline float b2f(unsigned short u) {
  unsigned int v = ((unsigned int)u) << 16; float f; __builtin_memcpy(&f, &v, 4); return f;
}
__device__ inline unsigned int pack2(float lo, float hi) {
  return ((unsigned int)f2b(hi) << 16) | (unsigned int)f2b(lo);
}
// async global->LDS, 16B per lane; LDS dest = wave-uniform base + lane*16
__device__ inline void gld16(const void* g, void* lds) {
  __builtin_amdgcn_global_load_lds((const __attribute__((address_space(1))) void*)g,
                                   (__attribute__((address_space(3))) void*)lds, 16, 0, 0);
}

// ---------- convert kernels ----------
__global__ void cvt_all_kernel(const float* __restrict__ x, const float* __restrict__ wq,
                               const float* __restrict__ wk, const float* __restrict__ wv,
                               const float* __restrict__ wo,
                               __hip_bfloat16* __restrict__ XB, __hip_bfloat16* __restrict__ WQKV,
                               __hip_bfloat16* __restrict__ WOb) {
  size_t i = ((size_t)blockIdx.x * 256 + threadIdx.x) * 8;
  const float* src; __hip_bfloat16* dst; size_t off;
  if (i < 4194304)      { src = x;  dst = XB;             off = i; }
  else if (i < 5242880) { src = wq; dst = WQKV;           off = i - 4194304; }
  else if (i < 6291456) { src = wk; dst = WQKV + 1048576; off = i - 5242880; }
  else if (i < 7340032) { src = wv; dst = WQKV + 2097152; off = i - 6291456; }
  else                  { src = wo; dst = WOb;            off = i - 7340032; }
  const float4* s4 = (const float4*)(src + off);
  float4 a = s4[0], b = s4[1];
  uint4 o;
  o.x = pack2(a.x, a.y); o.y = pack2(a.z, a.w);
  o.z = pack2(b.x, b.y); o.w = pack2(b.z, b.w);
  *(uint4*)(dst + off) = o;
}

// rpe_table [16][9999][64] f32 -> TBL [16][2048][64] bf16 (row 2047 zeroed)
__global__ void cvt_tbl_kernel(const float* __restrict__ tb, __hip_bfloat16* __restrict__ TBL) {
  size_t i = ((size_t)blockIdx.x * 256 + threadIdx.x) * 8;
  int h = (int)(i >> 17);
  int rem = (int)(i & 131071);
  int r = rem >> 6, c = rem & 63;
  uint4 o;
  if (r < 2047) {
    const float4* s4 = (const float4*)(tb + ((size_t)h * 9999 + r) * 64 + c);
    float4 a = s4[0], b = s4[1];
    o.x = pack2(a.x, a.y); o.y = pack2(a.z, a.w);
    o.z = pack2(b.x, b.y); o.w = pack2(b.z, b.w);
  } else { o.x = 0u; o.y = 0u; o.z = 0u; o.w = 0u; }
  *(uint4*)(TBL + i) = o;
}

// ---------- GEMM: C[m][n] = sum_k A[m][k]*Bt[n][k] (+bias), K=1024, tiles 128x128xBK64 ----------
// MODE 0: A=xb[4096][1024], Bt=w_qk[2048][1024] -> Q/K bf16 [B][H][S][64]
// MODE 1: A=wv[1024][1024], Bt=xb[4096][1024]  -> VT bf16 [B][H][64][S] (row bias)
// MODE 2: A=ctx[4096][1024], Bt=wo[1024][1024] -> d_out f32 [4096][1024]
template<int MODE>
__global__ __launch_bounds__(256, 3) void gemm_bt(
    const __hip_bfloat16* __restrict__ A,
    const __hip_bfloat16* __restrict__ Bt,
    const float* __restrict__ bias0,
    const float* __restrict__ bias1,
    void* __restrict__ out0,
    void* __restrict__ out1) {
  __shared__ __align__(16) char smem[32768];
  char* As = smem;
  char* Bs = smem + 16384;
  const int tid = threadIdx.x;
  const int w = tid >> 6, l = tid & 63;
  const int wr = w >> 1, wc = w & 1;
  const int lr = l & 15, lg = l >> 4;
  const int m0 = blockIdx.y * 128, n0 = blockIdx.x * 128;

  f32x4 acc[4][4] = {};

  for (int kt = 0; kt < 16; ++kt) {
    __syncthreads();
    #pragma unroll
    for (int i = 0; i < 4; ++i) {
      const int off = i * 4096 + w * 1024;  // wave-uniform LDS offset
      const int loff = off + l * 16;
      const int row = loff >> 7;
      const int cb = loff & 127;
      const int sc = cb ^ ((row & 7) << 4); // pre-swizzled global source (inverse of read swizzle)
      gld16((const char*)A  + (size_t)(m0 + row) * 2048 + kt * 128 + sc, As + off);
      gld16((const char*)Bt + (size_t)(n0 + row) * 2048 + kt * 128 + sc, Bs + off);
    }
    asm volatile("s_waitcnt vmcnt(0)" ::: "memory");
    __syncthreads();
    #pragma unroll
    for (int ks = 0; ks < 2; ++ks) {
      uint4 af[4], bf4[4];
      #pragma unroll
      for (int i = 0; i < 4; ++i) {
        const int ra = wr * 64 + i * 16 + lr;
        const int rb = wc * 64 + i * 16 + lr;
        const int cb = ks * 64 + lg * 16;
        af[i]  = *(const uint4*)(As + ra * 128 + (cb ^ ((ra & 7) << 4)));
        bf4[i] = *(const uint4*)(Bs + rb * 128 + (cb ^ ((rb & 7) << 4)));
      }
      #pragma unroll
      for (int i = 0; i < 4; ++i) {
        #pragma unroll
        for (int j = 0; j < 4; ++j)
          acc[i][j] = __builtin_amdgcn_mfma_f32_16x16x32_bf16(u4_to_s8(af[i]), u4_to_s8(bf4[j]), acc[i][j], 0, 0, 0);
      }
    }
  }

  const int mrow = m0 + wr * 64 + lg * 4;
  const int ncol = n0 + wc * 64 + lr;

  if constexpr (MODE == 0) {
    #pragma unroll
    for (int j = 0; j < 4; ++j) {
      const int n = ncol + j * 16;
      const bool isQ = n < 1024;
      __hip_bfloat16* op = isQ ? (__hip_bfloat16*)out0 : (__hip_bfloat16*)out1;
      const int nn = isQ ? n : n - 1024;
      const float bia = isQ ? bias0[n] : bias1[n - 1024];
      const int hh = nn >> 6, hd = nn & 63;
      #pragma unroll
      for (int i = 0; i < 4; ++i) {
        #pragma unroll
        for (int r = 0; r < 4; ++r) {
          const int m = mrow + i * 16 + r;
          const int bb = m >> 10, ss = m & 1023;
          op[(((size_t)(bb * 16 + hh)) * 1024 + ss) * 64 + hd] = __float2bfloat16(acc[i][j][r] + bia);
        }
      }
    }
  } else if constexpr (MODE == 1) {
    #pragma unroll
    for (int i = 0; i < 4; ++i) {
      #pragma unroll
      for (int r = 0; r < 4; ++r) {
        const int f = mrow + i * 16 + r;      // v feature = h*64+hd
        const float bia = bias0[f];
        const int fh = f >> 6, fd = f & 63;
        #pragma unroll
        for (int j = 0; j < 4; ++j) {
          const int bs = ncol + j * 16;
          const int bb = bs >> 10, ss = bs & 1023;
          ((__hip_bfloat16*)out0)[(size_t)bb * 1048576 + (size_t)fh * 65536 + fd * 1024 + ss] =
              __float2bfloat16(acc[i][j][r] + bia);
        }
      }
    }
  } else {
    #pragma unroll
    for (int j = 0; j < 4; ++j) {
      const int n = ncol + j * 16;
      const float bia = bias0[n];
      #pragma unroll
      for (int i = 0; i < 4; ++i) {
        #pragma unroll
        for (int r = 0; r < 4; ++r) {
          const int m = mrow + i * 16 + r;
          ((float*)out0)[(size_t)m * 1024 + n] = acc[i][j][r] + bia;
        }
      }
    }
  }
}

// ---------- fused attention with RPE ----------
// grid 512 = B(4) * H(16) * (S/128=8), 256 threads = 4 waves, each wave owns 32 q-rows.
// Swapped QK^T: sacc = mfma(Kfrag, Qfrag) -> S^T[k][q], col=lane&31=q (softmax lane-local).
// RPE: racc = mfma(Tbandfrag, Qfrag); diagonals stored skewed in LDS: REL[q][63-kl].
__global__ __launch_bounds__(256, 2) void attn_kernel(
    const __hip_bfloat16* __restrict__ Qg,   // [B][H][S][64]
    const __hip_bfloat16* __restrict__ Kg,   // [B][H][S][64]
    const __hip_bfloat16* __restrict__ VTg,  // [B][H][64][S]
    const __hip_bfloat16* __restrict__ Tg,   // [H][2048][64]
    __hip_bfloat16* __restrict__ Cg) {       // [B*S][1024]
  __shared__ __align__(16) char smem[57344];
  char* Klds = smem;            //  8 KB : K tile [64][64] bf16 (swizzled)
  char* Vlds = smem + 8192;     //  8 KB : V^T tile [64 d][64 k] bf16 (swizzled)
  char* Tlds = smem + 16384;    // 24 KB : table band [192][64] bf16 (swizzled)
  const int tid = threadIdx.x;
  const int w = tid >> 6, l = tid & 63;
  const int ql = l & 31, half = l >> 5;
  char* relw = smem + 40960 + w * 4096;  // per-wave [32 q][64 diag] bf16, XOR-swizzled

  const int bx = blockIdx.x;
  const int qt = bx & 7, h = (bx >> 3) & 15, b = bx >> 7;
  const int qb = qt * 128;
  const int q0 = qb + 32 * w;

  const size_t bh = (size_t)(b * 16 + h);
  const char* Qb = (const char*)Qg + bh * 131072;
  const char* Kb = (const char*)Kg + bh * 131072;
  const char* Vb = (const char*)VTg + bh * 131072;
  const char* Tb = (const char*)Tg + (size_t)h * 262144;

  // Q fragments (B-operand: lane holds Q[q0+ql][16*ds + 8*half + t])
  uint4 qf[4];
  {
    const char* qrow = Qb + (size_t)(q0 + ql) * 128 + half * 16;
    #pragma unroll
    for (int ds = 0; ds < 4; ++ds) qf[ds] = *(const uint4*)(qrow + ds * 32);
  }

  f32x16 cacc0 = {}, cacc1 = {};        // ctx[q over regs][d = dt*32 + lane]
  float m_run = -3.0e38f, l_run = 0.0f;
  const float LOG2E = 1.4426950408889634f;

  for (int kt = 0; kt < 16; ++kt) {
    const int k0 = kt * 64;
    __syncthreads();
    // ---- stage K (8KB) and V^T (8KB) ----
    #pragma unroll
    for (int i = 0; i < 2; ++i) {
      const int off = i * 4096 + w * 1024;
      const int loff = off + l * 16;
      const int row = loff >> 7, cb = loff & 127;
      const int sc = cb ^ ((row & 7) << 4);
      gld16(Kb + (size_t)(k0 + row) * 128 + sc, Klds + off);
      gld16(Vb + (size_t)row * 2048 + (size_t)k0 * 2 + sc, Vlds + off);
    }
    // ---- stage table band: rows rbase..rbase+191 (always within [0,2047]) ----
    {
      const int rbase = qb - k0 + 960;
      #pragma unroll
      for (int i = 0; i < 6; ++i) {
        const int off = i * 4096 + w * 1024;
        const int loff = off + l * 16;
        const int row = loff >> 7, cb = loff & 127;
        const int sc = cb ^ ((row & 7) << 4);
        gld16(Tb + (size_t)(rbase + row) * 128 + sc, Tlds + off);
      }
    }
    asm volatile("s_waitcnt vmcnt(0)" ::: "memory");
    __syncthreads();

    // ---- scores^T : 2 acc tiles (k-local 0..31, 32..63) ----
    f32x16 sacc0 = {}, sacc1 = {};
    #pragma unroll
    for (int ds = 0; ds < 4; ++ds) {
      const int cb = ds * 32 + half * 16;
      const int r0 = ql, r1 = 32 + ql;
      uint4 kf0 = *(const uint4*)(Klds + r0 * 128 + (cb ^ ((r0 & 7) << 4)));
      uint4 kf1 = *(const uint4*)(Klds + r1 * 128 + (cb ^ ((r1 & 7) << 4)));
      s8v qv = u4_to_s8(qf[ds]);
      sacc0 = __builtin_amdgcn_mfma_f32_32x32x16_bf16(u4_to_s8(kf0), qv, sacc0, 0, 0, 0);
      sacc1 = __builtin_amdgcn_mfma_f32_32x32x16_bf16(u4_to_s8(kf1), qv, sacc1, 0, 0, 0);
    }
    // ---- rel^T : 3 band tiles (wave band rows 32w + [0,96)) ----
    f32x16 racc0 = {}, racc1 = {}, racc2 = {};
    #pragma unroll
    for (int ds = 0; ds < 4; ++ds) {
      const int cb = ds * 32 + half * 16;
      const int t0 = 32 * w + ql, t1 = t0 + 32, t2 = t0 + 64;
      uint4 tf0 = *(const uint4*)(Tlds + t0 * 128 + (cb ^ ((t0 & 7) << 4)));
      uint4 tf1 = *(const uint4*)(Tlds + t1 * 128 + (cb ^ ((t1 & 7) << 4)));
      uint4 tf2 = *(const uint4*)(Tlds + t2 * 128 + (cb ^ ((t2 & 7) << 4)));
      s8v qv = u4_to_s8(qf[ds]);
      racc0 = __builtin_amdgcn_mfma_f32_32x32x16_bf16(u4_to_s8(tf0), qv, racc0, 0, 0, 0);
      racc1 = __builtin_amdgcn_mfma_f32_32x32x16_bf16(u4_to_s8(tf1), qv, racc1, 0, 0, 0);
      racc2 = __builtin_amdgcn_mfma_f32_32x32x16_bf16(u4_to_s8(tf2), qv, racc2, 0, 0, 0);
    }
    // ---- store diagonals: REL[ql][jj = bandrow - ql], keep jj in [0,64) ----
    #pragma unroll
    for (int r = 0; r < 16; ++r) {
      const int kr = (r & 3) + 8 * (r >> 2) + 4 * half;
      { const int jj = kr - ql;
        if (jj >= 0)
          *(unsigned short*)(relw + ql * 128 + ((jj * 2) ^ ((ql & 15) << 3))) = f2b(racc0[r]); }
      { const int jj = 32 + kr - ql;
        if (jj >= 0 && jj < 64)
          *(unsigned short*)(relw + ql * 128 + ((jj * 2) ^ ((ql & 15) << 3))) = f2b(racc1[r]); }
      { const int jj = 64 + kr - ql;
        if (jj < 64)
          *(unsigned short*)(relw + ql * 128 + ((jj * 2) ^ ((ql & 15) << 3))) = f2b(racc2[r]); }
    }
    // ---- gather + online softmax (all lane-local; cross-half via shfl_xor 32) ----
    float p0[16], p1[16];
    float pmax = -3.0e38f;
    #pragma unroll
    for (int r = 0; r < 16; ++r) {
      const int kr = (r & 3) + 8 * (r >> 2) + 4 * half;
      const int jj0 = 63 - kr;        // k-local = kr
      const int jj1 = 31 - kr;        // k-local = 32 + kr
      float rel0 = b2f(*(const unsigned short*)(relw + ql * 128 + ((jj0 * 2) ^ ((ql & 15) << 3))));
      float rel1 = b2f(*(const unsigned short*)(relw + ql * 128 + ((jj1 * 2) ^ ((ql & 15) << 3))));
      p0[r] = fmaf(sacc0[r], 0.125f, rel0);
      p1[r] = fmaf(sacc1[r], 0.125f, rel1);
      pmax = fmaxf(pmax, fmaxf(p0[r], p1[r]));
    }
    pmax = fmaxf(pmax, __shfl_xor(pmax, 32));
    const float m_new = fmaxf(m_run, pmax);
    const float corr = exp2f((m_run - m_new) * LOG2E);
    float psum = 0.0f;
    #pragma unroll
    for (int r = 0; r < 16; ++r) {
      p0[r] = exp2f((p0[r] - m_new) * LOG2E);
      p1[r] = exp2f((p1[r] - m_new) * LOG2E);
      psum += p0[r] + p1[r];
    }
    psum += __shfl_xor(psum, 32);
    l_run = fmaf(l_run, corr, psum);
    m_run = m_new;
    // rescale ctx: factor for q-row of each acc reg, broadcast from lane q
    #pragma unroll
    for (int r = 0; r < 16; ++r) {
      const float cr = __shfl(corr, (r & 3) + 8 * (r >> 2) + 4 * half);
      cacc0[r] *= cr;
      cacc1[r] *= cr;
    }
    // ---- pack P to bf16 words, exchange halves so each lane holds A-operand k-runs ----
    unsigned int w0[8], w1[8];
    #pragma unroll
    for (int jw = 0; jw < 8; ++jw) {
      w0[jw] = pack2(p0[2 * jw], p0[2 * jw + 1]);
      w1[jw] = pack2(p1[2 * jw], p1[2 * jw + 1]);
    }
    unsigned int r0x[4], r1x[4];
    #pragma unroll
    for (int i = 0; i < 4; ++i) {
      const int jkeep = (i & 1) + 4 * (i >> 1);      // {0,1,4,5}
      const int jsend = jkeep + 2;                   // {2,3,6,7}
      unsigned int v0 = half ? w0[jkeep] : w0[jsend];
      unsigned int v1 = half ? w1[jkeep] : w1[jsend];
      r0x[i] = (unsigned int)__shfl_xor((int)v0, 32);
      r1x[i] = (unsigned int)__shfl_xor((int)v1, 32);
    }
    // ---- PV: cacc[q][d] += P[q][k] * V[k][d] ----
    #pragma unroll
    for (int ks = 0; ks < 4; ++ks) {
      const int mm = ks & 1;
      unsigned int f0_, f1_, f2_, f3_;
      if (ks < 2) {
        f0_ = half ? r0x[2 * mm]     : w0[4 * mm];
        f1_ = half ? r0x[2 * mm + 1] : w0[4 * mm + 1];
        f2_ = half ? w0[4 * mm + 2]  : r0x[2 * mm];
        f3_ = half ? w0[4 * mm + 3]  : r0x[2 * mm + 1];
      } else {
        f0_ = half ? r1x[2 * mm]     : w1[4 * mm];
        f1_ = half ? r1x[2 * mm + 1] : w1[4 * mm + 1];
        f2_ = half ? w1[4 * mm + 2]  : r1x[2 * mm];
        f3_ = half ? w1[4 * mm + 3]  : r1x[2 * mm + 1];
      }
      s8v pf = words_to_s8(f0_, f1_, f2_, f3_);
      const int cb = ks * 32 + half * 16;
      const int vr0 = ql, vr1 = 32 + ql;
      uint4 vf0 = *(const uint4*)(Vlds + vr0 * 128 + (cb ^ ((vr0 & 7) << 4)));
      uint4 vf1 = *(const uint4*)(Vlds + vr1 * 128 + (cb ^ ((vr1 & 7) << 4)));
      cacc0 = __builtin_amdgcn_mfma_f32_32x32x16_bf16(pf, u4_to_s8(vf0), cacc0, 0, 0, 0);
      cacc1 = __builtin_amdgcn_mfma_f32_32x32x16_bf16(pf, u4_to_s8(vf1), cacc1, 0, 0, 0);
    }
  }

  // ---- epilogue: divide by row sum, store ctx bf16 (coalesced along d=lane) ----
  #pragma unroll
  for (int r = 0; r < 16; ++r) {
    const int qr = (r & 3) + 8 * (r >> 2) + 4 * half;
    const float inv = 1.0f / __shfl(l_run, qr);
    const size_t row = (size_t)b * 1024 + q0 + qr;
    const size_t basei = row * 1024 + h * 64 + ql;
    Cg[basei]      = __float2bfloat16(cacc0[r] * inv);
    Cg[basei + 32] = __float2bfloat16(cacc1[r] * inv);
  }
}

// ---------- launcher ----------
extern "C" void kernel_launch(void* const* d_in, const int* in_sizes, int n_in,
                              void* d_out, int out_size, void* d_ws, size_t ws_size,
                              hipStream_t stream) {
  (void)in_sizes; (void)n_in; (void)out_size; (void)ws_size;
  const float* x  = (const float*)d_in[0];
  const float* wq = (const float*)d_in[1];
  const float* bq = (const float*)d_in[2];
  const float* wk = (const float*)d_in[3];
  const float* bk = (const float*)d_in[4];
  const float* wv = (const float*)d_in[5];
  const float* bv = (const float*)d_in[6];
  const float* wo = (const float*)d_in[7];
  const float* bo = (const float*)d_in[8];
  const float* tb = (const float*)d_in[9];

  char* ws = (char*)d_ws;
  __hip_bfloat16* XB   = (__hip_bfloat16*)(ws);              // [4096][1024]
  __hip_bfloat16* WQKV = (__hip_bfloat16*)(ws + 8388608);    // [3072][1024] (wq|wk|wv)
  __hip_bfloat16* WOb  = (__hip_bfloat16*)(ws + 14680064);   // [1024][1024]
  __hip_bfloat16* TBL  = (__hip_bfloat16*)(ws + 16777216);   // [16][2048][64]
  __hip_bfloat16* QB   = (__hip_bfloat16*)(ws + 20971520);   // [4][16][1024][64]
  __hip_bfloat16* KB   = (__hip_bfloat16*)(ws + 29360128);   // [4][16][1024][64]
  __hip_bfloat16* VTB  = (__hip_bfloat16*)(ws + 37748736);   // [4][16][64][1024]
  __hip_bfloat16* CTX  = (__hip_bfloat16*)(ws + 46137344);   // [4096][1024]

  cvt_all_kernel<<<4096, 256, 0, stream>>>(x, wq, wk, wv, wo, XB, WQKV, WOb);
  cvt_tbl_kernel<<<1024, 256, 0, stream>>>(tb, TBL);
  gemm_bt<0><<<dim3(16, 32), 256, 0, stream>>>(XB, WQKV, bq, bk, (void*)QB, (void*)KB);
  gemm_bt<1><<<dim3(32, 8), 256, 0, stream>>>(WQKV + 2097152, XB, bv, nullptr, (void*)VTB, nullptr);
  attn_kernel<<<512, 256, 0, stream>>>(QB, KB, VTB, TBL, CTX);
  gemm_bt<2><<<dim3(8, 32), 256, 0, stream>>>(CTX, WOb, bo, nullptr, d_out, nullptr);
}

// Round 3
// 123.916 us; speedup vs baseline: 1.2452x; 1.2452x over previous
//
#include <hip/hip_runtime.h>
#include <hip/hip_bf16.h>
#include <stdint.h>

// ---------- types / helpers ----------
typedef __attribute__((ext_vector_type(8))) short s8v;      // 8 x bf16 (4 VGPR)
typedef __attribute__((ext_vector_type(4))) float f32x4;
typedef __attribute__((ext_vector_type(16))) float f32x16;

union V16 { uint4 u4; unsigned int u[4]; s8v s; };

__device__ inline s8v u4_to_s8(uint4 v) { V16 c; c.u4 = v; return c.s; }
__device__ inline s8v words_to_s8(unsigned int a, unsigned int b, unsigned int c, unsigned int d) {
  V16 t; t.u[0] = a; t.u[1] = b; t.u[2] = c; t.u[3] = d; return t.s;
}
__device__ inline unsigned short f2b(float f) {
  __hip_bfloat16 h = __float2bfloat16(f);
  unsigned short u; __builtin_memcpy(&u, &h, 2); return u;
}
__device__ inline unsigned int pack2(float lo, float hi) {
  return ((unsigned int)f2b(hi) << 16) | (unsigned int)f2b(lo);
}
// packed f32->bf16 pair (RNE), 1 instruction
__device__ inline unsigned int cvtpk(float lo, float hi) {
  unsigned int r; asm("v_cvt_pk_bf16_f32 %0, %1, %2" : "=v"(r) : "v"(lo), "v"(hi)); return r;
}
__device__ inline float exp2_fast(float x) {
#if __has_builtin(__builtin_amdgcn_exp2f)
  return __builtin_amdgcn_exp2f(x);
#else
  float y; asm("v_exp_f32 %0, %1" : "=v"(y) : "v"(x)); return y;
#endif
}
// async global->LDS, 16B per lane; LDS dest = wave-uniform base + lane*16
__device__ inline void gld16(const void* g, void* lds) {
  __builtin_amdgcn_global_load_lds((const __attribute__((address_space(1))) void*)g,
                                   (__attribute__((address_space(3))) void*)lds, 16, 0, 0);
}

#define LOG2E 1.4426950408889634f

// ---------- convert kernels ----------
__global__ void cvt_all_kernel(const float* __restrict__ x, const float* __restrict__ wq,
                               const float* __restrict__ wk, const float* __restrict__ wv,
                               const float* __restrict__ wo,
                               __hip_bfloat16* __restrict__ XB, __hip_bfloat16* __restrict__ WQKV,
                               __hip_bfloat16* __restrict__ WOb) {
  size_t i = ((size_t)blockIdx.x * 256 + threadIdx.x) * 8;
  const float* src; __hip_bfloat16* dst; size_t off;
  if (i < 4194304)      { src = x;  dst = XB;             off = i; }
  else if (i < 5242880) { src = wq; dst = WQKV;           off = i - 4194304; }
  else if (i < 6291456) { src = wk; dst = WQKV + 1048576; off = i - 5242880; }
  else if (i < 7340032) { src = wv; dst = WQKV + 2097152; off = i - 6291456; }
  else                  { src = wo; dst = WOb;            off = i - 7340032; }
  const float4* s4 = (const float4*)(src + off);
  float4 a = s4[0], b = s4[1];
  uint4 o;
  o.x = pack2(a.x, a.y); o.y = pack2(a.z, a.w);
  o.z = pack2(b.x, b.y); o.w = pack2(b.z, b.w);
  *(uint4*)(dst + off) = o;
}

// rpe_table [16][9999][64] f32 -> TBL [16][2048][64] bf16, PRE-SCALED by log2(e) (row 2047 zeroed)
__global__ void cvt_tbl_kernel(const float* __restrict__ tb, __hip_bfloat16* __restrict__ TBL) {
  size_t i = ((size_t)blockIdx.x * 256 + threadIdx.x) * 8;
  int h = (int)(i >> 17);
  int rem = (int)(i & 131071);
  int r = rem >> 6, c = rem & 63;
  uint4 o;
  if (r < 2047) {
    const float4* s4 = (const float4*)(tb + ((size_t)h * 9999 + r) * 64 + c);
    float4 a = s4[0], b = s4[1];
    o.x = pack2(a.x * LOG2E, a.y * LOG2E); o.y = pack2(a.z * LOG2E, a.w * LOG2E);
    o.z = pack2(b.x * LOG2E, b.y * LOG2E); o.w = pack2(b.z * LOG2E, b.w * LOG2E);
  } else { o.x = 0u; o.y = 0u; o.z = 0u; o.w = 0u; }
  *(uint4*)(TBL + i) = o;
}

// ---------- GEMM: C[m][n] = sum_k A[m][k]*Bt[n][k] (+bias), K=1024, tiles 128x128xBK64 ----------
// MODE 0: A=xb[4096][1024], Bt=w_qk[2048][1024] -> Q/K bf16 [B][H][S][64]; K scaled by 0.125*log2e
// MODE 1: A=wv[1024][1024], Bt=xb[4096][1024]  -> VT bf16 [B][H][64][S] (row bias)
// MODE 2: A=ctx[4096][1024], Bt=wo[1024][1024] -> d_out f32 [4096][1024]
template<int MODE>
__global__ __launch_bounds__(256, 3) void gemm_bt(
    const __hip_bfloat16* __restrict__ A,
    const __hip_bfloat16* __restrict__ Bt,
    const float* __restrict__ bias0,
    const float* __restrict__ bias1,
    void* __restrict__ out0,
    void* __restrict__ out1) {
  __shared__ __align__(16) char smem[32768];
  char* As = smem;
  char* Bs = smem + 16384;
  const int tid = threadIdx.x;
  const int w = tid >> 6, l = tid & 63;
  const int wr = w >> 1, wc = w & 1;
  const int lr = l & 15, lg = l >> 4;
  const int m0 = blockIdx.y * 128, n0 = blockIdx.x * 128;

  f32x4 acc[4][4] = {};

  for (int kt = 0; kt < 16; ++kt) {
    __syncthreads();
    #pragma unroll
    for (int i = 0; i < 4; ++i) {
      const int off = i * 4096 + w * 1024;  // wave-uniform LDS offset
      const int loff = off + l * 16;
      const int row = loff >> 7;
      const int cb = loff & 127;
      const int sc = cb ^ ((row & 7) << 4); // pre-swizzled global source (inverse of read swizzle)
      gld16((const char*)A  + (size_t)(m0 + row) * 2048 + kt * 128 + sc, As + off);
      gld16((const char*)Bt + (size_t)(n0 + row) * 2048 + kt * 128 + sc, Bs + off);
    }
    asm volatile("s_waitcnt vmcnt(0)" ::: "memory");
    __syncthreads();
    #pragma unroll
    for (int ks = 0; ks < 2; ++ks) {
      uint4 af[4], bf4[4];
      #pragma unroll
      for (int i = 0; i < 4; ++i) {
        const int ra = wr * 64 + i * 16 + lr;
        const int rb = wc * 64 + i * 16 + lr;
        const int cb = ks * 64 + lg * 16;
        af[i]  = *(const uint4*)(As + ra * 128 + (cb ^ ((ra & 7) << 4)));
        bf4[i] = *(const uint4*)(Bs + rb * 128 + (cb ^ ((rb & 7) << 4)));
      }
      #pragma unroll
      for (int i = 0; i < 4; ++i) {
        #pragma unroll
        for (int j = 0; j < 4; ++j)
          acc[i][j] = __builtin_amdgcn_mfma_f32_16x16x32_bf16(u4_to_s8(af[i]), u4_to_s8(bf4[j]), acc[i][j], 0, 0, 0);
      }
    }
  }

  const int mrow = m0 + wr * 64 + lg * 4;
  const int ncol = n0 + wc * 64 + lr;

  if constexpr (MODE == 0) {
    const float KSCALE = 0.125f * LOG2E;
    #pragma unroll
    for (int j = 0; j < 4; ++j) {
      const int n = ncol + j * 16;
      const bool isQ = n < 1024;
      __hip_bfloat16* op = isQ ? (__hip_bfloat16*)out0 : (__hip_bfloat16*)out1;
      const int nn = isQ ? n : n - 1024;
      const float bia = isQ ? bias0[n] : bias1[n - 1024];
      const float sc = isQ ? 1.0f : KSCALE;
      const int hh = nn >> 6, hd = nn & 63;
      #pragma unroll
      for (int i = 0; i < 4; ++i) {
        #pragma unroll
        for (int r = 0; r < 4; ++r) {
          const int m = mrow + i * 16 + r;
          const int bb = m >> 10, ss = m & 1023;
          op[(((size_t)(bb * 16 + hh)) * 1024 + ss) * 64 + hd] = __float2bfloat16((acc[i][j][r] + bia) * sc);
        }
      }
    }
  } else if constexpr (MODE == 1) {
    #pragma unroll
    for (int i = 0; i < 4; ++i) {
      #pragma unroll
      for (int r = 0; r < 4; ++r) {
        const int f = mrow + i * 16 + r;      // v feature = h*64+hd
        const float bia = bias0[f];
        const int fh = f >> 6, fd = f & 63;
        #pragma unroll
        for (int j = 0; j < 4; ++j) {
          const int bs = ncol + j * 16;
          const int bb = bs >> 10, ss = bs & 1023;
          ((__hip_bfloat16*)out0)[(size_t)bb * 1048576 + (size_t)fh * 65536 + fd * 1024 + ss] =
              __float2bfloat16(acc[i][j][r] + bia);
        }
      }
    }
  } else {
    #pragma unroll
    for (int j = 0; j < 4; ++j) {
      const int n = ncol + j * 16;
      const float bia = bias0[n];
      #pragma unroll
      for (int i = 0; i < 4; ++i) {
        #pragma unroll
        for (int r = 0; r < 4; ++r) {
          const int m = mrow + i * 16 + r;
          ((float*)out0)[(size_t)m * 1024 + n] = acc[i][j][r] + bia;
        }
      }
    }
  }
}

// ---------- fused attention with RPE (v3: f32 REL wrap-store with t=2 garbage mask) ----------
// grid 512 = B(4)*H(16)*(S/128=8), 256 threads = 4 waves, each wave owns 32 q-rows.
// Swapped QK^T: p = mfma(Kfrag, Qfrag) -> S^T[k][q], lane&31 = q (softmax lane-local).
// Scores arrive pre-scaled to log2 domain (K carries 0.125*log2e, T carries log2e).
// REL: racc = mfma(Tbandfrag, Qfrag); value (q=ql, k_local) stored f32 at REL[ql][k_local&63].
// Tile t covers k_local = ql+63-32t-kr: t=0 in [32,94] (wrap garbage -> [0,30], later fixed by
// t=2 valid), t=1 in [0,62] (all valid), t=2 in [-32,30] (garbage k_local<0 MUST be masked:
// it would overwrite t=0's valid [32,63] entries; same lane, same kr -> deterministic).
__global__ __launch_bounds__(256, 2) void attn_kernel(
    const __hip_bfloat16* __restrict__ Qg,   // [B][H][S][64]
    const __hip_bfloat16* __restrict__ Kg,   // [B][H][S][64] (pre-scaled)
    const __hip_bfloat16* __restrict__ VTg,  // [B][H][64][S]
    const __hip_bfloat16* __restrict__ Tg,   // [H][2048][64] (pre-scaled)
    __hip_bfloat16* __restrict__ Cg) {       // [B*S][1024]
  __shared__ __align__(16) char smem[73984];
  char* Klds = smem;            //  8 KB : K tile [64][64] bf16 (swizzled)
  char* Vlds = smem + 8192;     //  8 KB : V^T tile [64 d][64 k] bf16 (swizzled)
  char* Tlds = smem + 16384;    // 24 KB : 3 rolling slots x [64 rows][64] bf16 (swizzled)
  const int tid = threadIdx.x;
  const int w = tid >> 6, l = tid & 63;
  const int ql = l & 31, half = l >> 5;
  char* relw = smem + 40960 + w * 8192;  // per-wave [32 q][64 kl] f32, 16B-granule XOR swizzle
  char* dumpp = smem + 73728 + l * 4;    // garbage sink (256 B, shared; never read)

  const int bx = blockIdx.x;
  const int qt = bx & 7, h = (bx >> 3) & 15, b = bx >> 7;
  const int qb = qt * 128;
  const int q0 = qb + 32 * w;

  const size_t bh = (size_t)(b * 16 + h);
  const char* Qb = (const char*)Qg + bh * 131072;
  const char* Kb = (const char*)Kg + bh * 131072;
  const char* Vb = (const char*)VTg + bh * 131072;
  const char* Tb = (const char*)Tg + (size_t)h * 262144;

  // per-lane precomputed addressing
  const int relsw = ql * 256 + ((ql & 15) << 4);          // row base | swizzle (base mult of 256)
  const int u4 = (ql << 2) - (half << 4);                 // 4*(ql - 4*half)
  const int qlh = ql - 4 * half;                          // t=2 store valid iff (j+8g) < qlh
  const int k0sw = ql * 128 + ((ql & 7) << 4);            // K/V row ql, swizzled
  const int k1sw = (32 + ql) * 128 + ((ql & 7) << 4);     // K/V row 32+ql ((32+ql)&7 == ql&7)

  // Q fragments (B-operand: lane holds Q[q0+ql][16*ds + 8*half + t])
  s8v qv[4];
  {
    const char* qrow = Qb + (size_t)(q0 + ql) * 128 + half * 16;
    #pragma unroll
    for (int ds = 0; ds < 4; ++ds) qv[ds] = u4_to_s8(*(const uint4*)(qrow + ds * 32));
  }

  f32x16 cacc0 = {}, cacc1 = {};        // ctx[q over regs][d = tile*32 + lane]
  float mL = -1.0e30f, lsum = 0.0f;     // log2-domain running max / prob sum

  int rbase = qb + 960;                 // table band base row for kt=0 (decreases by 64/kt)

  for (int kt = 0; kt < 16; ++kt, rbase -= 64) {
    const int k0 = kt * 64;
    __syncthreads();
    // ---- stage K (8KB) and V^T (8KB) ----
    #pragma unroll
    for (int i = 0; i < 2; ++i) {
      const int off = i * 4096 + w * 1024;
      const int loff = off + l * 16;
      const int row = loff >> 7, cb = loff & 127;
      const int sc = cb ^ ((row & 7) << 4);
      gld16(Kb + (size_t)(k0 + row) * 128 + sc, Klds + off);
      gld16(Vb + (size_t)row * 2048 + (size_t)k0 * 2 + sc, Vlds + off);
    }
    // ---- stage table band chunk(s): rolling 3x64-row slots, slot = abs_chunk % 3 ----
    {
      const unsigned cb0 = (unsigned)(rbase >> 6);
      const int nstage = (kt == 0) ? 3 : 1;
      for (int j = 0; j < nstage; ++j) {
        const int slot = (int)((cb0 + (unsigned)j) % 3u);
        const char* src = Tb + (size_t)(rbase + 64 * j) * 128;
        char* dst = Tlds + slot * 8192;
        #pragma unroll
        for (int i = 0; i < 2; ++i) {
          const int off = i * 4096 + w * 1024;
          const int loff = off + l * 16;
          const int row = loff >> 7, cb = loff & 127;
          const int sc = cb ^ ((row & 7) << 4);
          gld16(src + (size_t)row * 128 + sc, dst + off);
        }
      }
    }
    asm volatile("s_waitcnt vmcnt(0)" ::: "memory");
    __syncthreads();

    __builtin_amdgcn_s_setprio(1);
    // ---- scores^T in log2 domain: p = K'.Q  (2 acc tiles: k-local 0..31 / 32..63) ----
    f32x16 p0 = {}, p1 = {};
    #pragma unroll
    for (int ds = 0; ds < 4; ++ds) {
      const int cb = ds * 32 + half * 16;
      uint4 kf0 = *(const uint4*)(Klds + (k0sw ^ cb));
      uint4 kf1 = *(const uint4*)(Klds + (k1sw ^ cb));
      p0 = __builtin_amdgcn_mfma_f32_32x32x16_bf16(u4_to_s8(kf0), qv[ds], p0, 0, 0, 0);
      p1 = __builtin_amdgcn_mfma_f32_32x32x16_bf16(u4_to_s8(kf1), qv[ds], p1, 0, 0, 0);
    }
    // ---- rel^T: 3 band tiles; store f32 diagonals, mod-64 wrap; mask t=2 garbage ----
    #pragma unroll
    for (int t = 0; t < 3; ++t) {
      const int slot = (int)(((unsigned)(rbase >> 6) + (unsigned)((w + t) >> 1)) % 3u);
      const int rowin = ((w + t) & 1) * 32 + ql;
      const int tbsw = slot * 8192 + rowin * 128 + ((ql & 7) << 4);
      f32x16 racc = {};
      #pragma unroll
      for (int ds = 0; ds < 4; ++ds) {
        const int cb = ds * 32 + half * 16;
        uint4 tf = *(const uint4*)(Tlds + (tbsw ^ cb));
        racc = __builtin_amdgcn_mfma_f32_32x32x16_bf16(u4_to_s8(tf), qv[ds], racc, 0, 0, 0);
      }
      #pragma unroll
      for (int g = 0; g < 4; ++g) {
        #pragma unroll
        for (int j = 0; j < 4; ++j) {
          const int C4 = 4 * (63 - 32 * t - j - 8 * g);   // compile-time
          char* dst = relw + (relsw ^ ((u4 + C4) & 252));
          if (t == 2) dst = (j + 8 * g < qlh) ? dst : dumpp;  // mask k_local<0 garbage
          *(float*)dst = racc[4 * g + j];
        }
      }
    }
    __builtin_amdgcn_s_setprio(0);

    // ---- gather rel quads (vectorized) + add to scores ----
    #pragma unroll
    for (int mp = 0; mp < 4; ++mp) {
      const int X0 = 32 * mp + 16 * half;
      f32x4 r0 = *(const f32x4*)(relw + (relsw ^ X0));
      f32x4 r1 = *(const f32x4*)(relw + (relsw ^ (X0 + 128)));
      #pragma unroll
      for (int j = 0; j < 4; ++j) {
        p0[4 * mp + j] += r0[j];
        p1[4 * mp + j] += r1[j];
      }
    }

    // ---- online softmax (log2 domain, defer-max) ----
    float pmax = p0[0];
    #pragma unroll
    for (int r = 1; r < 16; ++r) pmax = fmaxf(pmax, p0[r]);
    #pragma unroll
    for (int r = 0; r < 16; ++r) pmax = fmaxf(pmax, p1[r]);
    pmax = fmaxf(pmax, __shfl_xor(pmax, 32));
    if (!__all(pmax - mL <= 12.0f)) {
      const float mnew = fmaxf(mL, pmax);
      const float corr = exp2_fast(mL - mnew);
      mL = mnew;
      lsum *= corr;
      #pragma unroll
      for (int r = 0; r < 16; ++r) {
        const float cr = __shfl(corr, (r & 3) + 8 * (r >> 2) + 4 * half);
        cacc0[r] *= cr;
        cacc1[r] *= cr;
      }
    }
    float psum = 0.0f;
    #pragma unroll
    for (int r = 0; r < 16; ++r) {
      p0[r] = exp2_fast(p0[r] - mL);
      p1[r] = exp2_fast(p1[r] - mL);
      psum += p0[r] + p1[r];
    }
    psum += __shfl_xor(psum, 32);
    lsum += psum;

    // ---- pack P to bf16 words, exchange halves to build PV A-fragments ----
    unsigned int w0[8], w1[8];
    #pragma unroll
    for (int jw = 0; jw < 8; ++jw) {
      w0[jw] = cvtpk(p0[2 * jw], p0[2 * jw + 1]);
      w1[jw] = cvtpk(p1[2 * jw], p1[2 * jw + 1]);
    }
    unsigned int r0x[4], r1x[4];
    #pragma unroll
    for (int i = 0; i < 4; ++i) {
      const int jkeep = (i & 1) + 4 * (i >> 1);      // {0,1,4,5}
      const int jsend = jkeep + 2;                   // {2,3,6,7}
      unsigned int v0 = half ? w0[jkeep] : w0[jsend];
      unsigned int v1 = half ? w1[jkeep] : w1[jsend];
      r0x[i] = (unsigned int)__shfl_xor((int)v0, 32);
      r1x[i] = (unsigned int)__shfl_xor((int)v1, 32);
    }
    // ---- PV: cacc[q][d] += P[q][k] * V[k][d] ----
    __builtin_amdgcn_s_setprio(1);
    #pragma unroll
    for (int ks = 0; ks < 4; ++ks) {
      const int mm = ks & 1;
      unsigned int f0_, f1_, f2_, f3_;
      if (ks < 2) {
        f0_ = half ? r0x[2 * mm]     : w0[4 * mm];
        f1_ = half ? r0x[2 * mm + 1] : w0[4 * mm + 1];
        f2_ = half ? w0[4 * mm + 2]  : r0x[2 * mm];
        f3_ = half ? w0[4 * mm + 3]  : r0x[2 * mm + 1];
      } else {
        f0_ = half ? r1x[2 * mm]     : w1[4 * mm];
        f1_ = half ? r1x[2 * mm + 1] : w1[4 * mm + 1];
        f2_ = half ? w1[4 * mm + 2]  : r1x[2 * mm];
        f3_ = half ? w1[4 * mm + 3]  : r1x[2 * mm + 1];
      }
      s8v pf = words_to_s8(f0_, f1_, f2_, f3_);
      const int cb = ks * 32 + half * 16;
      uint4 vf0 = *(const uint4*)(Vlds + (k0sw ^ cb));
      uint4 vf1 = *(const uint4*)(Vlds + (k1sw ^ cb));
      cacc0 = __builtin_amdgcn_mfma_f32_32x32x16_bf16(pf, u4_to_s8(vf0), cacc0, 0, 0, 0);
      cacc1 = __builtin_amdgcn_mfma_f32_32x32x16_bf16(pf, u4_to_s8(vf1), cacc1, 0, 0, 0);
    }
    __builtin_amdgcn_s_setprio(0);
  }

  // ---- epilogue: divide by row sum, store ctx bf16 (coalesced along d=lane) ----
  #pragma unroll
  for (int r = 0; r < 16; ++r) {
    const int qr = (r & 3) + 8 * (r >> 2) + 4 * half;
    const float inv = 1.0f / __shfl(lsum, qr);
    const size_t row = (size_t)b * 1024 + q0 + qr;
    const size_t basei = row * 1024 + h * 64 + ql;
    Cg[basei]      = __float2bfloat16(cacc0[r] * inv);
    Cg[basei + 32] = __float2bfloat16(cacc1[r] * inv);
  }
}

// ---------- launcher ----------
extern "C" void kernel_launch(void* const* d_in, const int* in_sizes, int n_in,
                              void* d_out, int out_size, void* d_ws, size_t ws_size,
                              hipStream_t stream) {
  (void)in_sizes; (void)n_in; (void)out_size; (void)ws_size;
  const float* x  = (const float*)d_in[0];
  const float* wq = (const float*)d_in[1];
  const float* bq = (const float*)d_in[2];
  const float* wk = (const float*)d_in[3];
  const float* bk = (const float*)d_in[4];
  const float* wv = (const float*)d_in[5];
  const float* bv = (const float*)d_in[6];
  const float* wo = (const float*)d_in[7];
  const float* bo = (const float*)d_in[8];
  const float* tb = (const float*)d_in[9];

  char* ws = (char*)d_ws;
  __hip_bfloat16* XB   = (__hip_bfloat16*)(ws);              // [4096][1024]
  __hip_bfloat16* WQKV = (__hip_bfloat16*)(ws + 8388608);    // [3072][1024] (wq|wk|wv)
  __hip_bfloat16* WOb  = (__hip_bfloat16*)(ws + 14680064);   // [1024][1024]
  __hip_bfloat16* TBL  = (__hip_bfloat16*)(ws + 16777216);   // [16][2048][64]
  __hip_bfloat16* QB   = (__hip_bfloat16*)(ws + 20971520);   // [4][16][1024][64]
  __hip_bfloat16* KB   = (__hip_bfloat16*)(ws + 29360128);   // [4][16][1024][64]
  __hip_bfloat16* VTB  = (__hip_bfloat16*)(ws + 37748736);   // [4][16][64][1024]
  __hip_bfloat16* CTX  = (__hip_bfloat16*)(ws + 46137344);   // [4096][1024]

  cvt_all_kernel<<<4096, 256, 0, stream>>>(x, wq, wk, wv, wo, XB, WQKV, WOb);
  cvt_tbl_kernel<<<1024, 256, 0, stream>>>(tb, TBL);
  gemm_bt<0><<<dim3(16, 32), 256, 0, stream>>>(XB, WQKV, bq, bk, (void*)QB, (void*)KB);
  gemm_bt<1><<<dim3(32, 8), 256, 0, stream>>>(WQKV + 2097152, XB, bv, nullptr, (void*)VTB, nullptr);
  attn_kernel<<<512, 256, 0, stream>>>(QB, KB, VTB, TBL, CTX);
  gemm_bt<2><<<dim3(8, 32), 256, 0, stream>>>(CTX, WOb, bo, nullptr, d_out, nullptr);
}

// Round 4
// 113.918 us; speedup vs baseline: 1.3545x; 1.0878x over previous
//
#include <hip/hip_runtime.h>
#include <hip/hip_bf16.h>
#include <stdint.h>

// ---------- types / helpers ----------
typedef __attribute__((ext_vector_type(8))) short s8v;      // 8 x bf16 (4 VGPR)
typedef __attribute__((ext_vector_type(4))) float f32x4;
typedef __attribute__((ext_vector_type(16))) float f32x16;

union V16 { uint4 u4; unsigned int u[4]; s8v s; };

__device__ inline s8v u4_to_s8(uint4 v) { V16 c; c.u4 = v; return c.s; }
__device__ inline s8v words_to_s8(unsigned int a, unsigned int b, unsigned int c, unsigned int d) {
  V16 t; t.u[0] = a; t.u[1] = b; t.u[2] = c; t.u[3] = d; return t.s;
}
__device__ inline unsigned short f2b(float f) {
  __hip_bfloat16 h = __float2bfloat16(f);
  unsigned short u; __builtin_memcpy(&u, &h, 2); return u;
}
__device__ inline unsigned int pack2(float lo, float hi) {
  return ((unsigned int)f2b(hi) << 16) | (unsigned int)f2b(lo);
}
// packed f32->bf16 pair (RNE), 1 instruction
__device__ inline unsigned int cvtpk(float lo, float hi) {
  unsigned int r; asm("v_cvt_pk_bf16_f32 %0, %1, %2" : "=v"(r) : "v"(lo), "v"(hi)); return r;
}
__device__ inline float exp2_fast(float x) {
#if __has_builtin(__builtin_amdgcn_exp2f)
  return __builtin_amdgcn_exp2f(x);
#else
  float y; asm("v_exp_f32 %0, %1" : "=v"(y) : "v"(x)); return y;
#endif
}
// async global->LDS, 16B per lane; LDS dest = wave-uniform base + lane*16
__device__ inline void gld16(const void* g, void* lds) {
  __builtin_amdgcn_global_load_lds((const __attribute__((address_space(1))) void*)g,
                                   (__attribute__((address_space(3))) void*)lds, 16, 0, 0);
}

#define LOG2E 1.4426950408889634f

// ---------- fused convert kernel (x, wq, wk, wv, wo, rpe_table) ----------
__global__ void cvt_fused_kernel(const float* __restrict__ x, const float* __restrict__ wq,
                                 const float* __restrict__ wk, const float* __restrict__ wv,
                                 const float* __restrict__ wo, const float* __restrict__ tb,
                                 __hip_bfloat16* __restrict__ XB, __hip_bfloat16* __restrict__ WQKV,
                                 __hip_bfloat16* __restrict__ WOb, __hip_bfloat16* __restrict__ TBL) {
  const int bid = blockIdx.x;
  if (bid < 4096) {
    size_t i = ((size_t)bid * 256 + threadIdx.x) * 8;
    const float* src; __hip_bfloat16* dst; size_t off;
    if (i < 4194304)      { src = x;  dst = XB;             off = i; }
    else if (i < 5242880) { src = wq; dst = WQKV;           off = i - 4194304; }
    else if (i < 6291456) { src = wk; dst = WQKV + 1048576; off = i - 5242880; }
    else if (i < 7340032) { src = wv; dst = WQKV + 2097152; off = i - 6291456; }
    else                  { src = wo; dst = WOb;            off = i - 7340032; }
    const float4* s4 = (const float4*)(src + off);
    float4 a = s4[0], b = s4[1];
    uint4 o;
    o.x = pack2(a.x, a.y); o.y = pack2(a.z, a.w);
    o.z = pack2(b.x, b.y); o.w = pack2(b.z, b.w);
    *(uint4*)(dst + off) = o;
  } else {
    // rpe_table [16][9999][64] f32 -> TBL [16][2048][64] bf16, pre-scaled by log2e (row 2047 zero)
    size_t i = ((size_t)(bid - 4096) * 256 + threadIdx.x) * 8;
    int h = (int)(i >> 17);
    int rem = (int)(i & 131071);
    int r = rem >> 6, c = rem & 63;
    uint4 o;
    if (r < 2047) {
      const float4* s4 = (const float4*)(tb + ((size_t)h * 9999 + r) * 64 + c);
      float4 a = s4[0], b = s4[1];
      o.x = pack2(a.x * LOG2E, a.y * LOG2E); o.y = pack2(a.z * LOG2E, a.w * LOG2E);
      o.z = pack2(b.x * LOG2E, b.y * LOG2E); o.w = pack2(b.z * LOG2E, b.w * LOG2E);
    } else { o.x = 0u; o.y = 0u; o.z = 0u; o.w = 0u; }
    *(uint4*)(TBL + i) = o;
  }
}

// ---------- QKV GEMM: C[m][n] = XB[m]·WQKV[n] + bias, n-class -> Q / K(scaled) / VT ----------
// grid (24, 32): blockIdx.x tiles n (0-7 Q, 8-15 K, 16-23 V), blockIdx.y tiles m (s-rows)
__global__ __launch_bounds__(256, 3) void gemm_qkv(
    const __hip_bfloat16* __restrict__ A,      // XB [4096][1024]
    const __hip_bfloat16* __restrict__ Bt,     // WQKV [3072][1024]
    const float* __restrict__ bq, const float* __restrict__ bk, const float* __restrict__ bv,
    __hip_bfloat16* __restrict__ QB, __hip_bfloat16* __restrict__ KB,
    __hip_bfloat16* __restrict__ VTB) {
  __shared__ __align__(16) char smem[32768];
  char* As = smem;
  char* Bs = smem + 16384;
  const int tid = threadIdx.x;
  const int w = tid >> 6, l = tid & 63;
  const int wr = w >> 1, wc = w & 1;
  const int lr = l & 15, lg = l >> 4;
  const int m0 = blockIdx.y * 128, n0 = blockIdx.x * 128;

  f32x4 acc[4][4] = {};

  for (int kt = 0; kt < 16; ++kt) {
    __syncthreads();
    #pragma unroll
    for (int i = 0; i < 4; ++i) {
      const int off = i * 4096 + w * 1024;
      const int loff = off + l * 16;
      const int row = loff >> 7;
      const int cb = loff & 127;
      const int sc = cb ^ ((row & 7) << 4);
      gld16((const char*)A  + (size_t)(m0 + row) * 2048 + kt * 128 + sc, As + off);
      gld16((const char*)Bt + (size_t)(n0 + row) * 2048 + kt * 128 + sc, Bs + off);
    }
    asm volatile("s_waitcnt vmcnt(0)" ::: "memory");
    __syncthreads();
    #pragma unroll
    for (int ks = 0; ks < 2; ++ks) {
      uint4 af[4], bf4[4];
      #pragma unroll
      for (int i = 0; i < 4; ++i) {
        const int ra = wr * 64 + i * 16 + lr;
        const int rb = wc * 64 + i * 16 + lr;
        const int cb = ks * 64 + lg * 16;
        af[i]  = *(const uint4*)(As + ra * 128 + (cb ^ ((ra & 7) << 4)));
        bf4[i] = *(const uint4*)(Bs + rb * 128 + (cb ^ ((rb & 7) << 4)));
      }
      #pragma unroll
      for (int i = 0; i < 4; ++i) {
        #pragma unroll
        for (int j = 0; j < 4; ++j)
          acc[i][j] = __builtin_amdgcn_mfma_f32_16x16x32_bf16(u4_to_s8(af[i]), u4_to_s8(bf4[j]), acc[i][j], 0, 0, 0);
      }
    }
  }

  const int mrow = m0 + wr * 64 + lg * 4;
  const int ncol = n0 + wc * 64 + lr;
  const int cls = blockIdx.x >> 3;            // 0 = Q, 1 = K, 2 = V (block-uniform)

  if (cls < 2) {
    const float sc = cls ? 0.125f * LOG2E : 1.0f;
    const float* bias = cls ? bk : bq;
    __hip_bfloat16* op = cls ? KB : QB;
    #pragma unroll
    for (int j = 0; j < 4; ++j) {
      const int n = ncol - cls * 1024 + j * 16;
      const float bia = bias[n];
      const int hh = n >> 6, hd = n & 63;
      #pragma unroll
      for (int i = 0; i < 4; ++i) {
        #pragma unroll
        for (int r = 0; r < 4; ++r) {
          const int m = mrow + i * 16 + r;
          const int bb = m >> 10, ss = m & 1023;
          op[(((size_t)(bb * 16 + hh)) * 1024 + ss) * 64 + hd] = __float2bfloat16((acc[i][j][r] + bia) * sc);
        }
      }
    }
  } else {
    // V: write VT [B][H][64][S]; quad of consecutive s -> one 8B store
    #pragma unroll
    for (int j = 0; j < 4; ++j) {
      const int f = ncol - 2048 + j * 16;      // v feature = h*64+hd
      const float bia = bv[f];
      const int fh = f >> 6, fd = f & 63;
      #pragma unroll
      for (int i = 0; i < 4; ++i) {
        const int m = mrow + i * 16;          // quad m..m+3, m%4==0
        const int bb = m >> 10, ss = m & 1023;
        ushort4 qv;
        qv.x = f2b(acc[i][j][0] + bia); qv.y = f2b(acc[i][j][1] + bia);
        qv.z = f2b(acc[i][j][2] + bia); qv.w = f2b(acc[i][j][3] + bia);
        *(ushort4*)((char*)VTB + (((size_t)bb * 1048576 + (size_t)fh * 65536 + fd * 1024 + ss) * 2)) = qv;
      }
    }
  }
}

// ---------- out-proj GEMM: d_out[m][n] = CTX[m]·WOb[n] + bo, f32 out ----------
__global__ __launch_bounds__(256, 3) void gemm_out(
    const __hip_bfloat16* __restrict__ A,      // CTX [4096][1024]
    const __hip_bfloat16* __restrict__ Bt,     // WOb [1024][1024]
    const float* __restrict__ bo,
    float* __restrict__ out) {
  __shared__ __align__(16) char smem[32768];
  char* As = smem;
  char* Bs = smem + 16384;
  const int tid = threadIdx.x;
  const int w = tid >> 6, l = tid & 63;
  const int wr = w >> 1, wc = w & 1;
  const int lr = l & 15, lg = l >> 4;
  const int m0 = blockIdx.y * 128, n0 = blockIdx.x * 128;

  f32x4 acc[4][4] = {};

  for (int kt = 0; kt < 16; ++kt) {
    __syncthreads();
    #pragma unroll
    for (int i = 0; i < 4; ++i) {
      const int off = i * 4096 + w * 1024;
      const int loff = off + l * 16;
      const int row = loff >> 7;
      const int cb = loff & 127;
      const int sc = cb ^ ((row & 7) << 4);
      gld16((const char*)A  + (size_t)(m0 + row) * 2048 + kt * 128 + sc, As + off);
      gld16((const char*)Bt + (size_t)(n0 + row) * 2048 + kt * 128 + sc, Bs + off);
    }
    asm volatile("s_waitcnt vmcnt(0)" ::: "memory");
    __syncthreads();
    #pragma unroll
    for (int ks = 0; ks < 2; ++ks) {
      uint4 af[4], bf4[4];
      #pragma unroll
      for (int i = 0; i < 4; ++i) {
        const int ra = wr * 64 + i * 16 + lr;
        const int rb = wc * 64 + i * 16 + lr;
        const int cb = ks * 64 + lg * 16;
        af[i]  = *(const uint4*)(As + ra * 128 + (cb ^ ((ra & 7) << 4)));
        bf4[i] = *(const uint4*)(Bs + rb * 128 + (cb ^ ((rb & 7) << 4)));
      }
      #pragma unroll
      for (int i = 0; i < 4; ++i) {
        #pragma unroll
        for (int j = 0; j < 4; ++j)
          acc[i][j] = __builtin_amdgcn_mfma_f32_16x16x32_bf16(u4_to_s8(af[i]), u4_to_s8(bf4[j]), acc[i][j], 0, 0, 0);
      }
    }
  }

  const int mrow = m0 + wr * 64 + lg * 4;
  const int ncol = n0 + wc * 64 + lr;
  #pragma unroll
  for (int j = 0; j < 4; ++j) {
    const int n = ncol + j * 16;
    const float bia = bo[n];
    #pragma unroll
    for (int i = 0; i < 4; ++i) {
      #pragma unroll
      for (int r = 0; r < 4; ++r) {
        const int m = mrow + i * 16 + r;
        out[(size_t)m * 1024 + n] = acc[i][j][r] + bia;
      }
    }
  }
}

// ---------- fused attention with RPE (v4: software-pipelined, counted vmcnt) ----------
// grid 512 = B(4)*H(16)*(S/128=8) with XCD-chunk swizzle, 256 threads = 4 waves, 32 q-rows/wave.
// Pipeline per kt (issue order K,T,V keeps every wait at vmcnt(4); kt=0 prologue gives vmcnt(8)):
//   [vmcnt K;bar] QK^T | [bar] issue K(kt+1) | [vmcnt T;bar] REL | [bar] issue T(kt+1)
//   | softmax (VALU, covers in-flight loads) | [vmcnt V;bar] PV | [bar] issue V(kt+1)
// Buffer safety: K read only in QK^T, T-slot only in REL, V only in PV; each overwrite is
// issued after the barrier that proves all waves finished reading it.
__global__ __launch_bounds__(256, 2) void attn_kernel(
    const __hip_bfloat16* __restrict__ Qg,   // [B][H][S][64]
    const __hip_bfloat16* __restrict__ Kg,   // [B][H][S][64] (pre-scaled 0.125*log2e)
    const __hip_bfloat16* __restrict__ VTg,  // [B][H][64][S]
    const __hip_bfloat16* __restrict__ Tg,   // [H][2048][64] (pre-scaled log2e)
    __hip_bfloat16* __restrict__ Cg) {       // [B*S][1024]
  __shared__ __align__(16) char smem[73984];
  char* Klds = smem;            //  8 KB : K tile [64][64] bf16 (swizzled)
  char* Vlds = smem + 8192;     //  8 KB : V^T tile [64 d][64 k] bf16 (swizzled)
  char* Tlds = smem + 16384;    // 24 KB : 3 rolling slots x [64 rows][64] bf16 (swizzled)
  const int tid = threadIdx.x;
  const int w = tid >> 6, l = tid & 63;
  const int ql = l & 31, half = l >> 5;
  char* relw = smem + 40960 + w * 8192;  // per-wave [32 q][64 kl] f32, 16B-granule XOR swizzle
  char* dumpp = smem + 73728 + l * 4;    // garbage sink (256 B, shared; never read)

  // XCD-chunk swizzle: xcd = bx&7 under round-robin; give each XCD h in [2x,2x+2) x all qt x all b
  const int bx = blockIdx.x;
  const int work = (bx & 7) * 64 + (bx >> 3);
  const int b = work & 3, hqt = work >> 2;
  const int h = hqt >> 3, qt = hqt & 7;
  const int qb = qt * 128;
  const int q0 = qb + 32 * w;

  const size_t bh = (size_t)(b * 16 + h);
  const char* Qb = (const char*)Qg + bh * 131072;
  const char* Kb = (const char*)Kg + bh * 131072;
  const char* Vb = (const char*)VTg + bh * 131072;
  const char* Tb = (const char*)Tg + (size_t)h * 262144;

  // per-lane precomputed addressing
  const int relsw = ql * 256 + ((ql & 15) << 4);          // row base | swizzle
  const int u4 = (ql << 2) - (half << 4);                 // 4*(ql - 4*half)
  const int qlh = ql - 4 * half;                          // t=2 store valid iff (j+8g) < qlh
  const int k0sw = ql * 128 + ((ql & 7) << 4);            // K/V row ql, swizzled
  const int k1sw = (32 + ql) * 128 + ((ql & 7) << 4);     // K/V row 32+ql

  // staging lambdas (each = 2 gld16 = 2 vmcnt events per wave)
  auto stageK = [&](int k0n) {
    #pragma unroll
    for (int i = 0; i < 2; ++i) {
      const int off = i * 4096 + w * 1024;
      const int loff = off + l * 16;
      const int row = loff >> 7, cb = loff & 127;
      const int sc = cb ^ ((row & 7) << 4);
      gld16(Kb + (size_t)(k0n + row) * 128 + sc, Klds + off);
    }
  };
  auto stageV = [&](int k0n) {
    #pragma unroll
    for (int i = 0; i < 2; ++i) {
      const int off = i * 4096 + w * 1024;
      const int loff = off + l * 16;
      const int row = loff >> 7, cb = loff & 127;
      const int sc = cb ^ ((row & 7) << 4);
      gld16(Vb + (size_t)row * 2048 + (size_t)k0n * 2 + sc, Vlds + off);
    }
  };
  auto stageT = [&](int rbn) {
    const int slot = (int)(((unsigned)(rbn >> 6)) % 3u);
    char* dst = Tlds + slot * 8192;
    #pragma unroll
    for (int i = 0; i < 2; ++i) {
      const int off = i * 4096 + w * 1024;
      const int loff = off + l * 16;
      const int row = loff >> 7, cb = loff & 127;
      const int sc = cb ^ ((row & 7) << 4);
      gld16(Tb + (size_t)(rbn + row) * 128 + sc, dst + off);
    }
  };

  // Q fragments (B-operand: lane holds Q[q0+ql][16*ds + 8*half + t])
  s8v qv[4];
  {
    const char* qrow = Qb + (size_t)(q0 + ql) * 128 + half * 16;
    #pragma unroll
    for (int ds = 0; ds < 4; ++ds) qv[ds] = u4_to_s8(*(const uint4*)(qrow + ds * 32));
  }

  f32x16 cacc0 = {}, cacc1 = {};        // ctx[q over regs][d = tile*32 + lane]
  float mL = -1.0e30f, lsum = 0.0f;     // log2-domain running max / prob sum

  int rbase = qb + 960;                 // table band base row for kt=0 (decreases by 64/kt)

  // ---- prologue: issue K(0), T chunks(0), V(0) -> 10 outstanding, order K,T,V ----
  stageK(0);
  stageT(rbase); stageT(rbase + 64); stageT(rbase + 128);
  stageV(0);

  for (int kt = 0; kt < 16; ++kt, rbase -= 64) {
    // P1: K(kt) ready
    if (kt == 0) { asm volatile("s_waitcnt vmcnt(8)" ::: "memory"); }
    else         { asm volatile("s_waitcnt vmcnt(4)" ::: "memory"); }
    __builtin_amdgcn_s_barrier();

    // ---- QK^T in log2 domain (2 acc tiles: k-local 0..31 / 32..63) ----
    f32x16 p0 = {}, p1 = {};
    __builtin_amdgcn_s_setprio(1);
    #pragma unroll
    for (int ds = 0; ds < 4; ++ds) {
      const int cb = ds * 32 + half * 16;
      uint4 kf0 = *(const uint4*)(Klds + (k0sw ^ cb));
      uint4 kf1 = *(const uint4*)(Klds + (k1sw ^ cb));
      p0 = __builtin_amdgcn_mfma_f32_32x32x16_bf16(u4_to_s8(kf0), qv[ds], p0, 0, 0, 0);
      p1 = __builtin_amdgcn_mfma_f32_32x32x16_bf16(u4_to_s8(kf1), qv[ds], p1, 0, 0, 0);
    }
    __builtin_amdgcn_s_setprio(0);

    // P2: all waves done reading K -> prefetch K(kt+1) (kt=15: harmless dummy reload)
    __builtin_amdgcn_s_barrier();
    stageK(((kt + 1) & 15) * 64);

    // P3: newest T chunk ready (oldest 2 of the 6 outstanding are T)
    asm volatile("s_waitcnt vmcnt(4)" ::: "memory");
    __builtin_amdgcn_s_barrier();

    // ---- rel^T: 3 band tiles; store f32 diagonals, mod-64 wrap; mask t=2 garbage ----
    __builtin_amdgcn_s_setprio(1);
    #pragma unroll
    for (int t = 0; t < 3; ++t) {
      const int slot = (int)(((unsigned)(rbase >> 6) + (unsigned)((w + t) >> 1)) % 3u);
      const int rowin = ((w + t) & 1) * 32 + ql;
      const int tbsw = slot * 8192 + rowin * 128 + ((ql & 7) << 4);
      f32x16 racc = {};
      #pragma unroll
      for (int ds = 0; ds < 4; ++ds) {
        const int cb = ds * 32 + half * 16;
        uint4 tf = *(const uint4*)(Tlds + (tbsw ^ cb));
        racc = __builtin_amdgcn_mfma_f32_32x32x16_bf16(u4_to_s8(tf), qv[ds], racc, 0, 0, 0);
      }
      #pragma unroll
      for (int g = 0; g < 4; ++g) {
        #pragma unroll
        for (int j = 0; j < 4; ++j) {
          const int C4 = 4 * (63 - 32 * t - j - 8 * g);   // compile-time
          char* dst = relw + (relsw ^ ((u4 + C4) & 252));
          if (t == 2) dst = (j + 8 * g < qlh) ? dst : dumpp;  // mask k_local<0 garbage
          *(float*)dst = racc[4 * g + j];
        }
      }
    }
    __builtin_amdgcn_s_setprio(0);

    // P4: oldest T slot consumed -> prefetch T chunk for kt+1 (clamped at the end)
    __builtin_amdgcn_s_barrier();
    { int rbn = rbase - 64; if (rbn < 0) rbn = 0; stageT(rbn); }

    // ---- gather rel quads (vectorized) + add to scores ----
    #pragma unroll
    for (int mp = 0; mp < 4; ++mp) {
      const int X0 = 32 * mp + 16 * half;
      f32x4 r0 = *(const f32x4*)(relw + (relsw ^ X0));
      f32x4 r1 = *(const f32x4*)(relw + (relsw ^ (X0 + 128)));
      #pragma unroll
      for (int j = 0; j < 4; ++j) {
        p0[4 * mp + j] += r0[j];
        p1[4 * mp + j] += r1[j];
      }
    }

    // ---- online softmax (log2 domain, defer-max, tree reductions) ----
    float mx[8];
    #pragma unroll
    for (int i = 0; i < 8; ++i)
      mx[i] = fmaxf(fmaxf(p0[2 * i], p0[2 * i + 1]), fmaxf(p1[2 * i], p1[2 * i + 1]));
    float pmax = fmaxf(fmaxf(fmaxf(mx[0], mx[1]), fmaxf(mx[2], mx[3])),
                       fmaxf(fmaxf(mx[4], mx[5]), fmaxf(mx[6], mx[7])));
    pmax = fmaxf(pmax, __shfl_xor(pmax, 32));
    if (!__all(pmax - mL <= 12.0f)) {
      const float mnew = fmaxf(mL, pmax);
      const float corr = exp2_fast(mL - mnew);
      mL = mnew;
      lsum *= corr;
      #pragma unroll
      for (int r = 0; r < 16; ++r) {
        const float cr = __shfl(corr, (r & 3) + 8 * (r >> 2) + 4 * half);
        cacc0[r] *= cr;
        cacc1[r] *= cr;
      }
    }
    #pragma unroll
    for (int r = 0; r < 16; ++r) {
      p0[r] = exp2_fast(p0[r] - mL);
      p1[r] = exp2_fast(p1[r] - mL);
    }
    float sm[8];
    #pragma unroll
    for (int i = 0; i < 8; ++i)
      sm[i] = (p0[2 * i] + p0[2 * i + 1]) + (p1[2 * i] + p1[2 * i + 1]);
    float psum = ((sm[0] + sm[1]) + (sm[2] + sm[3])) + ((sm[4] + sm[5]) + (sm[6] + sm[7]));
    psum += __shfl_xor(psum, 32);
    lsum += psum;

    // ---- pack P to bf16 words, exchange halves to build PV A-fragments ----
    unsigned int w0[8], w1[8];
    #pragma unroll
    for (int jw = 0; jw < 8; ++jw) {
      w0[jw] = cvtpk(p0[2 * jw], p0[2 * jw + 1]);
      w1[jw] = cvtpk(p1[2 * jw], p1[2 * jw + 1]);
    }
    unsigned int r0x[4], r1x[4];
    #pragma unroll
    for (int i = 0; i < 4; ++i) {
      const int jkeep = (i & 1) + 4 * (i >> 1);      // {0,1,4,5}
      const int jsend = jkeep + 2;                   // {2,3,6,7}
      unsigned int v0 = half ? w0[jkeep] : w0[jsend];
      unsigned int v1 = half ? w1[jkeep] : w1[jsend];
      r0x[i] = (unsigned int)__shfl_xor((int)v0, 32);
      r1x[i] = (unsigned int)__shfl_xor((int)v1, 32);
    }

    // P5: V(kt) ready (oldest 2 of the 6 outstanding are V)
    asm volatile("s_waitcnt vmcnt(4)" ::: "memory");
    __builtin_amdgcn_s_barrier();

    // ---- PV: cacc[q][d] += P[q][k] * V[k][d] ----
    __builtin_amdgcn_s_setprio(1);
    #pragma unroll
    for (int ks = 0; ks < 4; ++ks) {
      const int mm = ks & 1;
      unsigned int f0_, f1_, f2_, f3_;
      if (ks < 2) {
        f0_ = half ? r0x[2 * mm]     : w0[4 * mm];
        f1_ = half ? r0x[2 * mm + 1] : w0[4 * mm + 1];
        f2_ = half ? w0[4 * mm + 2]  : r0x[2 * mm];
        f3_ = half ? w0[4 * mm + 3]  : r0x[2 * mm + 1];
      } else {
        f0_ = half ? r1x[2 * mm]     : w1[4 * mm];
        f1_ = half ? r1x[2 * mm + 1] : w1[4 * mm + 1];
        f2_ = half ? w1[4 * mm + 2]  : r1x[2 * mm];
        f3_ = half ? w1[4 * mm + 3]  : r1x[2 * mm + 1];
      }
      s8v pf = words_to_s8(f0_, f1_, f2_, f3_);
      const int cb = ks * 32 + half * 16;
      uint4 vf0 = *(const uint4*)(Vlds + (k0sw ^ cb));
      uint4 vf1 = *(const uint4*)(Vlds + (k1sw ^ cb));
      cacc0 = __builtin_amdgcn_mfma_f32_32x32x16_bf16(pf, u4_to_s8(vf0), cacc0, 0, 0, 0);
      cacc1 = __builtin_amdgcn_mfma_f32_32x32x16_bf16(pf, u4_to_s8(vf1), cacc1, 0, 0, 0);
    }
    __builtin_amdgcn_s_setprio(0);

    // P6: all waves done reading V -> prefetch V(kt+1)
    __builtin_amdgcn_s_barrier();
    stageV(((kt + 1) & 15) * 64);
  }
  asm volatile("s_waitcnt vmcnt(0)" ::: "memory");   // drain dummy prefetches before endpgm

  // ---- epilogue: divide by row sum, store ctx bf16 (coalesced along d=lane) ----
  #pragma unroll
  for (int r = 0; r < 16; ++r) {
    const int qr = (r & 3) + 8 * (r >> 2) + 4 * half;
    const float inv = 1.0f / __shfl(lsum, qr);
    const size_t row = (size_t)b * 1024 + q0 + qr;
    const size_t basei = row * 1024 + h * 64 + ql;
    Cg[basei]      = __float2bfloat16(cacc0[r] * inv);
    Cg[basei + 32] = __float2bfloat16(cacc1[r] * inv);
  }
}

// ---------- launcher ----------
extern "C" void kernel_launch(void* const* d_in, const int* in_sizes, int n_in,
                              void* d_out, int out_size, void* d_ws, size_t ws_size,
                              hipStream_t stream) {
  (void)in_sizes; (void)n_in; (void)out_size; (void)ws_size;
  const float* x  = (const float*)d_in[0];
  const float* wq = (const float*)d_in[1];
  const float* bq = (const float*)d_in[2];
  const float* wk = (const float*)d_in[3];
  const float* bk = (const float*)d_in[4];
  const float* wv = (const float*)d_in[5];
  const float* bv = (const float*)d_in[6];
  const float* wo = (const float*)d_in[7];
  const float* bo = (const float*)d_in[8];
  const float* tb = (const float*)d_in[9];

  char* ws = (char*)d_ws;
  __hip_bfloat16* XB   = (__hip_bfloat16*)(ws);              // [4096][1024]
  __hip_bfloat16* WQKV = (__hip_bfloat16*)(ws + 8388608);    // [3072][1024] (wq|wk|wv)
  __hip_bfloat16* WOb  = (__hip_bfloat16*)(ws + 14680064);   // [1024][1024]
  __hip_bfloat16* TBL  = (__hip_bfloat16*)(ws + 16777216);   // [16][2048][64]
  __hip_bfloat16* QB   = (__hip_bfloat16*)(ws + 20971520);   // [4][16][1024][64]
  __hip_bfloat16* KB   = (__hip_bfloat16*)(ws + 29360128);   // [4][16][1024][64]
  __hip_bfloat16* VTB  = (__hip_bfloat16*)(ws + 37748736);   // [4][16][64][1024]
  __hip_bfloat16* CTX  = (__hip_bfloat16*)(ws + 46137344);   // [4096][1024]

  cvt_fused_kernel<<<5120, 256, 0, stream>>>(x, wq, wk, wv, wo, tb, XB, WQKV, WOb, TBL);
  gemm_qkv<<<dim3(24, 32), 256, 0, stream>>>(XB, WQKV, bq, bk, bv, QB, KB, VTB);
  attn_kernel<<<512, 256, 0, stream>>>(QB, KB, VTB, TBL, CTX);
  gemm_out<<<dim3(8, 32), 256, 0, stream>>>(CTX, WOb, bo, (float*)d_out);
}